// Round 6
// baseline (181.119 us; speedup 1.0000x reference)
//
#include <hip/hip_runtime.h>
#include <math.h>

// AdaptiveTripletMarginLoss: B=65536 rows, D=256 fp32.
// R5: R4's deep bursts + sub-capacity self-balancing grid.
//  - 8 rows/wave/iter; each load instr = one full row (64 lanes x float4)
//  - 24 nontemporal 1-KiB loads issued before first consumption
//  - 1024 blocks (4/CU, below the 8/CU cap) + grid-stride: exactly 2
//    bursts/wave, no exact-fill generation cliff, self-load-balancing
//  - two-kernel finish (d_ws partials + final_reduce)

#define D 256
#define TPB 256
#define ROWS_PER_WAVE 8
#define WAVES_PER_BLOCK 4
#define NBLOCKS 1024

typedef float nt_float4 __attribute__((ext_vector_type(4)));

__global__ __launch_bounds__(TPB, 4) void triplet_partial(
    const nt_float4* __restrict__ a4, const nt_float4* __restrict__ p4,
    const nt_float4* __restrict__ n4, float* __restrict__ partial, int B)
{
    const int lane = threadIdx.x & 63;
    const int wib  = threadIdx.x >> 6;
    const int waveId = blockIdx.x * WAVES_PER_BLOCK + wib;
    const int nWaves = gridDim.x * WAVES_PER_BLOCK;
    const int nGroups = B / ROWS_PER_WAVE;   // 8192 row-groups of 8

    float local = 0.0f;

    for (int g = waveId; g < nGroups; g += nWaves) {
        const size_t base = (size_t)g * ROWS_PER_WAVE * 64 + lane;

        nt_float4 av[ROWS_PER_WAVE], pv[ROWS_PER_WAVE], nv[ROWS_PER_WAVE];
        #pragma unroll
        for (int j = 0; j < ROWS_PER_WAVE; ++j)
            av[j] = __builtin_nontemporal_load(a4 + base + (size_t)j * 64);
        #pragma unroll
        for (int j = 0; j < ROWS_PER_WAVE; ++j)
            pv[j] = __builtin_nontemporal_load(p4 + base + (size_t)j * 64);
        #pragma unroll
        for (int j = 0; j < ROWS_PER_WAVE; ++j)
            nv[j] = __builtin_nontemporal_load(n4 + base + (size_t)j * 64);

        float sap[ROWS_PER_WAVE], san[ROWS_PER_WAVE], spn[ROWS_PER_WAVE];
        #pragma unroll
        for (int j = 0; j < ROWS_PER_WAVE; ++j) {
            float d, s0, s1, s2;
            d = av[j].x - pv[j].x; s0 = d * d;
            d = av[j].y - pv[j].y; s0 = fmaf(d, d, s0);
            d = av[j].z - pv[j].z; s0 = fmaf(d, d, s0);
            d = av[j].w - pv[j].w; s0 = fmaf(d, d, s0);
            d = av[j].x - nv[j].x; s1 = d * d;
            d = av[j].y - nv[j].y; s1 = fmaf(d, d, s1);
            d = av[j].z - nv[j].z; s1 = fmaf(d, d, s1);
            d = av[j].w - nv[j].w; s1 = fmaf(d, d, s1);
            d = pv[j].x - nv[j].x; s2 = d * d;
            d = pv[j].y - nv[j].y; s2 = fmaf(d, d, s2);
            d = pv[j].z - nv[j].z; s2 = fmaf(d, d, s2);
            d = pv[j].w - nv[j].w; s2 = fmaf(d, d, s2);
            sap[j] = s0; san[j] = s1; spn[j] = s2;
        }

        // full 64-lane butterfly all-reduce of all 24 accumulators
        #pragma unroll
        for (int off = 32; off >= 1; off >>= 1) {
            #pragma unroll
            for (int j = 0; j < ROWS_PER_WAVE; ++j) {
                sap[j] += __shfl_xor(sap[j], off, 64);
                san[j] += __shfl_xor(san[j], off, 64);
                spn[j] += __shfl_xor(spn[j], off, 64);
            }
        }

        if (lane == 0) {
            #pragma unroll
            for (int j = 0; j < ROWS_PER_WAVE; ++j) {
                const float dap = sqrtf(sap[j]);
                const float dan = sqrtf(san[j]);
                const float dpn = sqrtf(spn[j]);
                // exp(4*dap) ~ exp(90) -> inf -> term 0 (matches ref fp32)
                const float msim = 1.0f + 2.0f / (__expf(4.0f * dap) + 1e-6f);
                // exp(-4*dan+4) underflows vs 1e-6 -> term ~2e6 (dominates)
                const float mdis = 1.0f + 2.0f / (__expf(-4.0f * dan + 4.0f) + 1e-6f);
                local += dap - 0.5f * (dan + dpn) + msim + mdis;
            }
        }
    }

    __shared__ float sm[WAVES_PER_BLOCK];
    if (lane == 0) sm[wib] = local;
    __syncthreads();
    if (threadIdx.x == 0) {
        float s = 0.0f;
        #pragma unroll
        for (int i = 0; i < WAVES_PER_BLOCK; ++i) s += sm[i];
        partial[blockIdx.x] = s;
    }
}

__global__ __launch_bounds__(256) void final_reduce(
    const float* __restrict__ partial, float* __restrict__ out,
    int nPartial, float invB)
{
    float s = 0.0f;
    for (int i = threadIdx.x; i < nPartial; i += blockDim.x) s += partial[i];
    #pragma unroll
    for (int off = 32; off > 0; off >>= 1) s += __shfl_xor(s, off, 64);

    __shared__ float sm[4];
    const int lane = threadIdx.x & 63;
    const int w = threadIdx.x >> 6;
    if (lane == 0) sm[w] = s;
    __syncthreads();
    if (threadIdx.x == 0) out[0] = (sm[0] + sm[1] + sm[2] + sm[3]) * invB;
}

extern "C" void kernel_launch(void* const* d_in, const int* in_sizes, int n_in,
                              void* d_out, int out_size, void* d_ws, size_t ws_size,
                              hipStream_t stream) {
    const nt_float4* a = (const nt_float4*)d_in[0];
    const nt_float4* p = (const nt_float4*)d_in[1];
    const nt_float4* n = (const nt_float4*)d_in[2];
    float* out = (float*)d_out;
    float* partial = (float*)d_ws;   // NBLOCKS floats (4 KiB) scratch

    const int B = in_sizes[0] / D;   // 65536

    triplet_partial<<<NBLOCKS, TPB, 0, stream>>>(a, p, n, partial, B);
    final_reduce<<<1, 256, 0, stream>>>(partial, out, NBLOCKS, 1.0f / (float)B);
}